// Round 1
// baseline (1052.374 us; speedup 1.0000x reference)
//
#include <hip/hip_runtime.h>
#include <hip/hip_bf16.h>

// EmbeddingCrossAttention on MI355X (gfx950). f32 in/out, bf16 MFMA compute.
//
// softmax over single kv slot == 1  =>  ctx = v  =>  everything is affine:
//   t = text@Wt^T+bt ; a = audio@Wa^T+ba
//   t_ctx = a@Wvo^T + bvo            (Wvo = Wo.Wv, bvo = Wo.bv + bo)
//   logit_t = t@Wgt1^T + a@(Wgt2.Wvo)^T + (bgt + Wgt2.bvo)
//   refined_t = g*t + (1-g)*t_ctx, g = sigmoid(logit_t)   (audio swapped)
//
// Round-5 changes (rocprof: fused_gate MfmaUtil 16%, HBM 10.6%, Occ 11% ->
// latency-bound on per-K-step vmcnt(0) drain; FETCH 147.7 MB vs ~102 ideal ->
// B-panel L2 thrash):
//   1. XCD mapping = n-panel (natural blockIdx order; removed m-keyed swizzle).
//      8 n-panels == 8 XCDs -> each XCD's weight slice (<=768 KB) is
//      L2-resident; X streams from L3. Fixes the weight over-fetch.
//   2. Double-buffered LDS + prefetch (T3 minimum 2-phase): issue next tile's
//      global_load_lds BEFORE computing current tile; ONE __syncthreads per
//      K-step (its vmcnt(0) only drains loads in flight across the whole
//      compute phase). Applied to gemm_bt and fused_gate.
//   3. Gate-weight folds consolidated: one M=2048 GEMM (128 blocks) computes
//      both Wgt2.Wvo and Wga2.Wvo; fused kernel takes separate Wg1/Wg2vo
//      pointers (no "cat" layout). 4 fold GEMMs -> 3.

typedef __attribute__((ext_vector_type(8))) short short8;
typedef __attribute__((ext_vector_type(4))) float floatx4;

__device__ __forceinline__ float bf2f(__hip_bfloat16 x) { return __bfloat162float(x); }

__device__ __forceinline__ void gl_lds16(const void* g, void* l) {
  __builtin_amdgcn_global_load_lds(
      (const __attribute__((address_space(1))) unsigned int*)g,
      (__attribute__((address_space(3))) unsigned int*)l,
      16, 0, 0);
}

// Strided f32 -> bf16 convert. One row per blockIdx.y, 4 cols per thread.
__global__ __launch_bounds__(256)
void cvt_kernel(const float* __restrict__ src, int sld,
                __hip_bfloat16* __restrict__ dst, int dld, int cols4) {
  const int r = blockIdx.y;
  const int c4 = blockIdx.x * 256 + threadIdx.x;
  if (c4 >= cols4) return;
  const float4 v = *(const float4*)(src + (size_t)r * sld + c4 * 4);
  union { __hip_bfloat16 h[4]; uint2 u; } o;
  o.h[0] = __float2bfloat16(v.x);
  o.h[1] = __float2bfloat16(v.y);
  o.h[2] = __float2bfloat16(v.z);
  o.h[3] = __float2bfloat16(v.w);
  *(uint2*)(dst + (size_t)r * dld + c4 * 4) = o.u;
}

// Transposed convert: dst[c][r] = bf16(src[r][c]), R=C=1024.
__global__ __launch_bounds__(256)
void cvt_t_kernel(const float* __restrict__ src, __hip_bfloat16* __restrict__ dst,
                  int R, int C) {
  __shared__ float tile[32][33];
  const int tx = threadIdx.x, ty = threadIdx.y;  // block (32, 8)
  const int bx = blockIdx.x * 32, by = blockIdx.y * 32;
#pragma unroll
  for (int i = 0; i < 32; i += 8)
    tile[ty + i][tx] = src[(size_t)(by + ty + i) * C + bx + tx];
  __syncthreads();
#pragma unroll
  for (int i = 0; i < 32; i += 8)
    dst[(size_t)(bx + ty + i) * R + by + tx] = __float2bfloat16(tile[tx][ty + i]);
}

// y[r] = sum_k W[r*ld + coff + k] * x[k] + b[r],  K = 1024. 4 rows/block.
__global__ __launch_bounds__(256)
void mv_kernel(const float* __restrict__ W, int ld, int coff,
               const float* __restrict__ x, const float* __restrict__ b,
               float* __restrict__ y) {
  const int lane = threadIdx.x & 63;
  const int row = blockIdx.x * 4 + (threadIdx.x >> 6);
  float acc = 0.f;
  for (int k = lane; k < 1024; k += 64)
    acc += W[(size_t)row * ld + coff + k] * x[k];
#pragma unroll
  for (int off = 32; off > 0; off >>= 1) acc += __shfl_down(acc, off);
  if (lane == 0) y[row] = acc + b[row];
}

// C = A @ W^T (+bias), bf16 out. A row-major (M x K) bf16, W (N x K) bf16.
// C[m*ldc + coff + n]. Double-buffered LDS, one barrier per K-step.
__global__ __launch_bounds__(256)
void gemm_bt_kernel(const __hip_bfloat16* __restrict__ A,
                    const __hip_bfloat16* __restrict__ W,
                    const float* __restrict__ bias,
                    __hip_bfloat16* __restrict__ C,
                    int K, int ldc, int coff) {
  constexpr int BK = 32;
  __shared__ __align__(16) __hip_bfloat16 lA[2 * 128 * BK];
  __shared__ __align__(16) __hip_bfloat16 lB[2 * 128 * BK];

  const int tid  = threadIdx.x;
  const int lane = tid & 63;
  const int wave = tid >> 6;
  const int wm = wave & 1;
  const int wn = wave >> 1;
  const int m0 = blockIdx.y * 128;   // natural mapping: XCD = blockIdx.x = n-panel
  const int n0 = blockIdx.x * 128;

  floatx4 acc[4][4];
#pragma unroll
  for (int i = 0; i < 4; ++i)
#pragma unroll
    for (int j = 0; j < 4; ++j) {
      floatx4 z = {0.f, 0.f, 0.f, 0.f};
      acc[i][j] = z;
    }

  const int srow = tid >> 2;
  const int scol = (tid & 3) * 8;
  const int fr = lane & 15;
  const int fq = (lane >> 4) * 8;

  auto stage = [&](int k0, int buf) {
    const __hip_bfloat16* srcA = A + (size_t)m0 * K + k0;
    const __hip_bfloat16* srcB = W + (size_t)n0 * K + k0;
#pragma unroll
    for (int p = 0; p < 2; ++p) {
      const int row = p * 64 + srow;
      gl_lds16(srcA + (size_t)row * K + scol, (char*)lA + buf * 8192 + p * 4096 + tid * 16);
      gl_lds16(srcB + (size_t)row * K + scol, (char*)lB + buf * 8192 + p * 4096 + tid * 16);
    }
  };

  const int NT = K / BK;
  stage(0, 0);
  __syncthreads();

  for (int t = 0; t < NT; ++t) {
    const int cur = t & 1;
    if (t + 1 < NT) stage((t + 1) * BK, cur ^ 1);  // prefetch overlaps compute

    const short* sA = (const short*)lA + cur * 4096;
    const short* sB = (const short*)lB + cur * 4096;
    short8 af[4], bfr[4];
#pragma unroll
    for (int i = 0; i < 4; ++i)
      af[i] = *(const short8*)(sA + (wm * 64 + i * 16 + fr) * BK + fq);
#pragma unroll
    for (int j = 0; j < 4; ++j)
      bfr[j] = *(const short8*)(sB + (wn * 64 + j * 16 + fr) * BK + fq);
#pragma unroll
    for (int i = 0; i < 4; ++i)
#pragma unroll
      for (int j = 0; j < 4; ++j)
        acc[i][j] = __builtin_amdgcn_mfma_f32_16x16x32_bf16(af[i], bfr[j], acc[i][j], 0, 0, 0);
    __syncthreads();  // vmcnt(0): drains prefetch; barrier: protects buf swap
  }

  const int col = lane & 15;
  const int rq  = (lane >> 4) * 4;
#pragma unroll
  for (int j = 0; j < 4; ++j) {
    const int n = n0 + wn * 64 + j * 16 + col;
    const float bv = bias ? bias[n] : 0.f;
#pragma unroll
    for (int i = 0; i < 4; ++i)
#pragma unroll
      for (int r = 0; r < 4; ++r) {
        const int m = m0 + wm * 64 + i * 16 + rq + r;
        C[(size_t)m * ldc + coff + n] = __float2bfloat16(acc[i][j][r] + bv);
      }
  }
}

// Fused ctx + gate kernel (per modality), N = 1024. 64 virtual K-tiles:
//   t in [0,32):  accL += Xs_tile @ Wg1_tile^T
//   t in [32,64): accL += Xo_tile @ Wg2vo_tile^T ; accC += Xo_tile @ Wvo_tile^T
//   out[m,n] = g*Xs[m,n] + (1-g)*(accC+bvo),  g = sigmoid(accL+bg)   (f32 out)
__global__ __launch_bounds__(256)
void fused_gate_kernel(const __hip_bfloat16* __restrict__ Xs,
                       const __hip_bfloat16* __restrict__ Xo,
                       const __hip_bfloat16* __restrict__ Wg1,    // 1024 x 1024
                       const __hip_bfloat16* __restrict__ Wg2vo,  // 1024 x 1024
                       const __hip_bfloat16* __restrict__ Wvo,    // 1024 x 1024
                       const float* __restrict__ bg,
                       const float* __restrict__ bvo,
                       float* __restrict__ out) {
  constexpr int BK = 32;
  __shared__ __align__(16) __hip_bfloat16 lA[2 * 128 * BK];
  __shared__ __align__(16) __hip_bfloat16 lB[2 * 128 * BK];
  __shared__ __align__(16) __hip_bfloat16 lC[2 * 128 * BK];

  const int tid  = threadIdx.x;
  const int lane = tid & 63;
  const int wave = tid >> 6;
  const int wm = wave & 1;
  const int wn = wave >> 1;
  const int m0 = blockIdx.y * 128;   // natural mapping: XCD = blockIdx.x = n-panel
  const int n0 = blockIdx.x * 128;

  floatx4 accL[4][4], accC[4][4];
#pragma unroll
  for (int i = 0; i < 4; ++i)
#pragma unroll
    for (int j = 0; j < 4; ++j) {
      floatx4 z = {0.f, 0.f, 0.f, 0.f};
      accL[i][j] = z;
      accC[i][j] = z;
    }

  const int srow = tid >> 2;
  const int scol = (tid & 3) * 8;
  const int fr = lane & 15;
  const int fq = (lane >> 4) * 8;

  auto stage = [&](int t, int buf) {
    const int k0 = (t & 31) * BK;
    const __hip_bfloat16* srcA = (t < 32 ? Xs : Xo) + (size_t)m0 * 1024 + k0;
    const __hip_bfloat16* srcB = (t < 32 ? Wg1 : Wg2vo) + (size_t)n0 * 1024 + k0;
#pragma unroll
    for (int p = 0; p < 2; ++p) {
      const int row = p * 64 + srow;
      gl_lds16(srcA + (size_t)row * 1024 + scol, (char*)lA + buf * 8192 + p * 4096 + tid * 16);
      gl_lds16(srcB + (size_t)row * 1024 + scol, (char*)lB + buf * 8192 + p * 4096 + tid * 16);
    }
    if (t >= 32) {
      const __hip_bfloat16* srcC = Wvo + (size_t)n0 * 1024 + k0;
#pragma unroll
      for (int p = 0; p < 2; ++p) {
        const int row = p * 64 + srow;
        gl_lds16(srcC + (size_t)row * 1024 + scol, (char*)lC + buf * 8192 + p * 4096 + tid * 16);
      }
    }
  };

  stage(0, 0);
  __syncthreads();

  for (int t = 0; t < 64; ++t) {
    const int cur = t & 1;
    if (t < 63) stage(t + 1, cur ^ 1);  // prefetch overlaps compute

    const short* sA = (const short*)lA + cur * 4096;
    const short* sB = (const short*)lB + cur * 4096;
    short8 af[4], bfr[4];
#pragma unroll
    for (int i = 0; i < 4; ++i)
      af[i] = *(const short8*)(sA + (wm * 64 + i * 16 + fr) * BK + fq);
#pragma unroll
    for (int j = 0; j < 4; ++j)
      bfr[j] = *(const short8*)(sB + (wn * 64 + j * 16 + fr) * BK + fq);

    if (t < 32) {
#pragma unroll
      for (int i = 0; i < 4; ++i)
#pragma unroll
        for (int j = 0; j < 4; ++j)
          accL[i][j] = __builtin_amdgcn_mfma_f32_16x16x32_bf16(af[i], bfr[j], accL[i][j], 0, 0, 0);
    } else {
      const short* sC = (const short*)lC + cur * 4096;
      short8 cfr[4];
#pragma unroll
      for (int j = 0; j < 4; ++j)
        cfr[j] = *(const short8*)(sC + (wn * 64 + j * 16 + fr) * BK + fq);
#pragma unroll
      for (int i = 0; i < 4; ++i)
#pragma unroll
        for (int j = 0; j < 4; ++j) {
          accL[i][j] = __builtin_amdgcn_mfma_f32_16x16x32_bf16(af[i], bfr[j], accL[i][j], 0, 0, 0);
          accC[i][j] = __builtin_amdgcn_mfma_f32_16x16x32_bf16(af[i], cfr[j], accC[i][j], 0, 0, 0);
        }
    }
    __syncthreads();
  }

  // epilogue: D mapping col = lane&15, row = (lane>>4)*4 + reg
  const int col = lane & 15;
  const int rq  = (lane >> 4) * 4;
#pragma unroll
  for (int j = 0; j < 4; ++j) {
    const int n = n0 + wn * 64 + j * 16 + col;
    const float bgv = bg[n];
    const float bcv = bvo[n];
#pragma unroll
    for (int i = 0; i < 4; ++i)
#pragma unroll
      for (int r = 0; r < 4; ++r) {
        const int m = m0 + wm * 64 + i * 16 + rq + r;
        const size_t idx = (size_t)m * 1024 + n;
        const float lg = accL[i][j][r] + bgv;
        const float cv = accC[i][j][r] + bcv;
        const float xv = bf2f(Xs[idx]);
        const float g = 1.f / (1.f + __expf(-lg));
        out[idx] = g * xv + (1.f - g) * cv;
      }
  }
}

extern "C" void kernel_launch(void* const* d_in, const int* in_sizes, int n_in,
                              void* d_out, int out_size, void* d_ws, size_t ws_size,
                              hipStream_t stream) {
  (void)in_sizes; (void)n_in; (void)out_size; (void)ws_size;

  const float* text  = (const float*)d_in[0];
  const float* audio = (const float*)d_in[1];
  const float* Wt  = (const float*)d_in[2];
  const float* bt  = (const float*)d_in[3];
  const float* Wa  = (const float*)d_in[4];
  const float* ba  = (const float*)d_in[5];
  // d_in[6..9] = Wq,bq,Wk,bk: dead (softmax over single kv slot == 1)
  const float* Wv  = (const float*)d_in[10];
  const float* bv  = (const float*)d_in[11];
  const float* Wo  = (const float*)d_in[12];
  const float* bo  = (const float*)d_in[13];
  const float* Wgt = (const float*)d_in[14];
  const float* bgt = (const float*)d_in[15];
  const float* Wga = (const float*)d_in[16];
  const float* bga = (const float*)d_in[17];

  const size_t BE = 16384ull * 1024;
  const size_t M1 = 1024ull * 1024;
  float* out = (float*)d_out;

  // ws (persistent across chain): ~79.5 MB (< 92 MB proven-safe budget)
  __hip_bfloat16* p = (__hip_bfloat16*)d_ws;
  __hip_bfloat16* X      = p; p += 2 * BE;         // [t ; a], 64 MB
  __hip_bfloat16* Wt_b   = p; p += 768ull * 1024;
  __hip_bfloat16* Wa_b   = p; p += M1;
  __hip_bfloat16* Wo_b   = p; p += M1;
  __hip_bfloat16* Wvo_b  = p; p += M1;
  __hip_bfloat16* Wg1t_b = p; p += M1;             // Wgt[:, :1024]
  __hip_bfloat16* Wg1a_b = p; p += M1;             // Wga[:, :1024]
  __hip_bfloat16* G2vo   = p; p += 2 * M1;         // [Wgt2.Wvo ; Wga2.Wvo], 2048x1024
  float* bvo  = (float*)p;
  float* bgtp = bvo + 1024;
  float* bgap = bvo + 2048;

  // d_out transient scratch (~66.5 MB, all dead before fused kernels write f32 out)
  __hip_bfloat16* scr     = (__hip_bfloat16*)d_out;
  __hip_bfloat16* text_b  = scr;                          // 16384x768
  __hip_bfloat16* audio_b = scr + 16384ull * 768;         // 16384x1024
  __hip_bfloat16* WvT_b   = audio_b + BE;                 // Wv^T
  __hip_bfloat16* WvoT_b  = WvT_b + M1;                   // Wvo^T
  __hip_bfloat16* G2      = WvoT_b + M1;                  // [Wgt2 ; Wga2], 2048x1024

  dim3 blk(256, 1, 1);

  // ---- converts ----
  cvt_kernel<<<dim3(1, 16384), blk, 0, stream>>>(text, 768, text_b, 768, 192);
  cvt_kernel<<<dim3(1, 16384), blk, 0, stream>>>(audio, 1024, audio_b, 1024, 256);
  cvt_kernel<<<dim3(1, 768), blk, 0, stream>>>(Wt, 1024, Wt_b, 1024, 256);
  cvt_kernel<<<dim3(1, 1024), blk, 0, stream>>>(Wa, 1024, Wa_b, 1024, 256);
  cvt_kernel<<<dim3(1, 1024), blk, 0, stream>>>(Wo, 1024, Wo_b, 1024, 256);
  cvt_t_kernel<<<dim3(32, 32), dim3(32, 8), 0, stream>>>(Wv, WvT_b, 1024, 1024);
  cvt_kernel<<<dim3(1, 1024), blk, 0, stream>>>(Wgt, 2048, Wg1t_b, 1024, 256);        // Wgt1
  cvt_kernel<<<dim3(1, 1024), blk, 0, stream>>>(Wgt + 1024, 2048, G2, 1024, 256);     // Wgt2
  cvt_kernel<<<dim3(1, 1024), blk, 0, stream>>>(Wga, 2048, Wg1a_b, 1024, 256);        // Wga1
  cvt_kernel<<<dim3(1, 1024), blk, 0, stream>>>(Wga + 1024, 2048, G2 + M1, 1024, 256);// Wga2

  // ---- bias folds (f32) ----
  mv_kernel<<<dim3(256), blk, 0, stream>>>(Wo, 1024, 0, bv, bo, bvo);         // bvo = Wo.bv + bo
  mv_kernel<<<dim3(256), blk, 0, stream>>>(Wgt, 2048, 1024, bvo, bgt, bgtp);  // bgt' = Wgt2.bvo + bgt
  mv_kernel<<<dim3(256), blk, 0, stream>>>(Wga, 2048, 1024, bvo, bga, bgap);

  // ---- weight folds (bf16 GEMMs) ----
  // Wvo[n,k]  = sum_m Wo[n,m] WvT[k,m]
  gemm_bt_kernel<<<dim3(8, 8), blk, 0, stream>>>(Wo_b, WvT_b, nullptr, Wvo_b, 1024, 1024, 0);
  // WvoT[k,n] = sum_m WvT[k,m] Wo[n,m]
  gemm_bt_kernel<<<dim3(8, 8), blk, 0, stream>>>(WvT_b, Wo_b, nullptr, WvoT_b, 1024, 1024, 0);
  // G2vo[m,n] = sum_k G2[m,k] WvoT[n,k] = (Wg2.Wvo)[m,n], both modalities stacked
  gemm_bt_kernel<<<dim3(8, 16), blk, 0, stream>>>(G2, WvoT_b, nullptr, G2vo, 1024, 1024, 0);

  // ---- projections ----
  dim3 g1(8, 128);
  gemm_bt_kernel<<<g1, blk, 0, stream>>>(text_b, Wt_b, bt, X, 768, 1024, 0);
  gemm_bt_kernel<<<g1, blk, 0, stream>>>(audio_b, Wa_b, ba, X + BE, 1024, 1024, 0);

  // ---- fused ctx + gate (f32 out, in final position) ----
  fused_gate_kernel<<<g1, blk, 0, stream>>>(X, X + BE, Wg1t_b, G2vo, Wvo_b, bgtp, bvo, out);
  fused_gate_kernel<<<g1, blk, 0, stream>>>(X + BE, X, Wg1a_b, G2vo + M1, Wvo_b, bgap, bvo, out + BE);
}

// Round 2
// 926.629 us; speedup vs baseline: 1.1357x; 1.1357x over previous
//
#include <hip/hip_runtime.h>
#include <hip/hip_bf16.h>

// EmbeddingCrossAttention on MI355X (gfx950). f32 in/out, bf16 MFMA compute.
//
// softmax over single kv slot == 1  =>  ctx = v  =>  everything is affine:
//   t = text@Wt^T+bt ; a = audio@Wa^T+ba
//   t_ctx = a@Wvo^T + bvo            (Wvo = Wo.Wv, bvo = Wo.bv + bo)
//   logit_t = t@Wgt1^T + a@(Wgt2.Wvo)^T + (bgt + Wgt2.bvo)
//   refined_t = g*t + (1-g)*t_ctx, g = sigmoid(logit_t)   (audio swapped)
//
// Round-6 (post-mortem of round-5 regression):
//   - REVERTED to m-keyed XCD swizzle (round-5 natural order doubled FETCH
//     147.7->290.9 MB: A-slices L2-missed on all 8 XCDs; old swizzle keeps
//     the A-tile L2-resident across its n-sweep).
//   - REVERTED double-buffer prefetch (branchy stage lambda doubled VALU
//     busy 44->101 us with zero MFMA gain).
//   - NEW: BK=64 (was 32). Halves the per-K-step barrier+vmcnt(0) drains
//     (the measured stall: 67% of cycles no pipe issuing). LDS 48KB fused /
//     32KB gemm -> still 3 blocks/CU (VGPR-capped). Fragments read per
//     k-slice (h-loop) so register pressure is unchanged vs BK=32.
//   - kept: 3 weight-fold GEMMs (stacked G2), separate Wg1/Wg2vo pointers.

typedef __attribute__((ext_vector_type(8))) short short8;
typedef __attribute__((ext_vector_type(4))) float floatx4;

__device__ __forceinline__ float bf2f(__hip_bfloat16 x) { return __bfloat162float(x); }

__device__ __forceinline__ void gl_lds16(const void* g, void* l) {
  __builtin_amdgcn_global_load_lds(
      (const __attribute__((address_space(1))) unsigned int*)g,
      (__attribute__((address_space(3))) unsigned int*)l,
      16, 0, 0);
}

// XCD-aware block swizzle. Requires gridDim.x == 8 (n-blocks), gridDim.y % 8 == 0
// (or small grids as used by the fold GEMMs). All same-m blocks get
// lid % 8 == m % 8 -> same XCD, spaced 8 lids apart -> the A-tile stays in
// that XCD's L2 across its n-sweep (FETCH 147.7 MB vs 290.9 without).
__device__ __forceinline__ void swizzle_mn(int& m_idx, int& n_idx) {
  const int lid = blockIdx.y * 8 + blockIdx.x;
  m_idx = (lid >> 6) * 8 + (lid & 7);
  n_idx = (lid >> 3) & 7;
}

// Strided f32 -> bf16 convert. One row per blockIdx.y, 4 cols per thread.
__global__ __launch_bounds__(256)
void cvt_kernel(const float* __restrict__ src, int sld,
                __hip_bfloat16* __restrict__ dst, int dld, int cols4) {
  const int r = blockIdx.y;
  const int c4 = blockIdx.x * 256 + threadIdx.x;
  if (c4 >= cols4) return;
  const float4 v = *(const float4*)(src + (size_t)r * sld + c4 * 4);
  union { __hip_bfloat16 h[4]; uint2 u; } o;
  o.h[0] = __float2bfloat16(v.x);
  o.h[1] = __float2bfloat16(v.y);
  o.h[2] = __float2bfloat16(v.z);
  o.h[3] = __float2bfloat16(v.w);
  *(uint2*)(dst + (size_t)r * dld + c4 * 4) = o.u;
}

// Transposed convert: dst[c][r] = bf16(src[r][c]), R=C=1024.
__global__ __launch_bounds__(256)
void cvt_t_kernel(const float* __restrict__ src, __hip_bfloat16* __restrict__ dst,
                  int R, int C) {
  __shared__ float tile[32][33];
  const int tx = threadIdx.x, ty = threadIdx.y;  // block (32, 8)
  const int bx = blockIdx.x * 32, by = blockIdx.y * 32;
#pragma unroll
  for (int i = 0; i < 32; i += 8)
    tile[ty + i][tx] = src[(size_t)(by + ty + i) * C + bx + tx];
  __syncthreads();
#pragma unroll
  for (int i = 0; i < 32; i += 8)
    dst[(size_t)(bx + ty + i) * R + by + tx] = __float2bfloat16(tile[tx][ty + i]);
}

// y[r] = sum_k W[r*ld + coff + k] * x[k] + b[r],  K = 1024. 4 rows/block.
__global__ __launch_bounds__(256)
void mv_kernel(const float* __restrict__ W, int ld, int coff,
               const float* __restrict__ x, const float* __restrict__ b,
               float* __restrict__ y) {
  const int lane = threadIdx.x & 63;
  const int row = blockIdx.x * 4 + (threadIdx.x >> 6);
  float acc = 0.f;
  for (int k = lane; k < 1024; k += 64)
    acc += W[(size_t)row * ld + coff + k] * x[k];
#pragma unroll
  for (int off = 32; off > 0; off >>= 1) acc += __shfl_down(acc, off);
  if (lane == 0) y[row] = acc + b[row];
}

// C = A @ W^T (+bias), bf16 out. A row-major (M x K) bf16, W (N x K) bf16.
// C[m*ldc + coff + n]. Single-buffered LDS, BK=64 (16-32 barrier drains total).
__global__ __launch_bounds__(256)
void gemm_bt_kernel(const __hip_bfloat16* __restrict__ A,
                    const __hip_bfloat16* __restrict__ W,
                    const float* __restrict__ bias,
                    __hip_bfloat16* __restrict__ C,
                    int K, int ldc, int coff) {
  constexpr int BK = 64;
  __shared__ __align__(16) __hip_bfloat16 lA[128 * BK];
  __shared__ __align__(16) __hip_bfloat16 lB[128 * BK];

  const int tid  = threadIdx.x;
  const int lane = tid & 63;
  const int wave = tid >> 6;
  const int wm = wave & 1;
  const int wn = wave >> 1;
  int m_idx, n_idx;
  swizzle_mn(m_idx, n_idx);
  const int m0 = m_idx * 128;
  const int n0 = n_idx * 128;

  floatx4 acc[4][4];
#pragma unroll
  for (int i = 0; i < 4; ++i)
#pragma unroll
    for (int j = 0; j < 4; ++j) {
      floatx4 z = {0.f, 0.f, 0.f, 0.f};
      acc[i][j] = z;
    }

  const int srow = tid >> 3;          // 32 rows per staging round
  const int scol = (tid & 7) * 8;     // 8 threads x 16B = 128B row
  const int fr = lane & 15;
  const int fq = (lane >> 4) * 8;

  for (int k0 = 0; k0 < K; k0 += BK) {
    const __hip_bfloat16* srcA = A + (size_t)m0 * K + k0;
    const __hip_bfloat16* srcB = W + (size_t)n0 * K + k0;
#pragma unroll
    for (int p = 0; p < 4; ++p) {
      const int row = p * 32 + srow;
      gl_lds16(srcA + (size_t)row * K + scol, (char*)lA + p * 4096 + tid * 16);
      gl_lds16(srcB + (size_t)row * K + scol, (char*)lB + p * 4096 + tid * 16);
    }
    __syncthreads();

#pragma unroll
    for (int h = 0; h < 2; ++h) {
      short8 af[4], bfr[4];
#pragma unroll
      for (int i = 0; i < 4; ++i)
        af[i] = *(const short8*)((const short*)lA + (wm * 64 + i * 16 + fr) * BK + h * 32 + fq);
#pragma unroll
      for (int j = 0; j < 4; ++j)
        bfr[j] = *(const short8*)((const short*)lB + (wn * 64 + j * 16 + fr) * BK + h * 32 + fq);
#pragma unroll
      for (int i = 0; i < 4; ++i)
#pragma unroll
        for (int j = 0; j < 4; ++j)
          acc[i][j] = __builtin_amdgcn_mfma_f32_16x16x32_bf16(af[i], bfr[j], acc[i][j], 0, 0, 0);
    }
    __syncthreads();
  }

  const int col = lane & 15;
  const int rq  = (lane >> 4) * 4;
#pragma unroll
  for (int j = 0; j < 4; ++j) {
    const int n = n0 + wn * 64 + j * 16 + col;
    const float bv = bias ? bias[n] : 0.f;
#pragma unroll
    for (int i = 0; i < 4; ++i)
#pragma unroll
      for (int r = 0; r < 4; ++r) {
        const int m = m0 + wm * 64 + i * 16 + rq + r;
        C[(size_t)m * ldc + coff + n] = __float2bfloat16(acc[i][j][r] + bv);
      }
  }
}

// Fused ctx + gate kernel (per modality), N = 1024:
//   phase 1: accL += Xs @ Wg1^T
//   phase 2: accL += Xo @ Wg2vo^T ; accC += Xo @ Wvo^T
//   out[m,n] = g*Xs[m,n] + (1-g)*(accC+bvo),  g = sigmoid(accL+bg)   (f32 out)
__global__ __launch_bounds__(256)
void fused_gate_kernel(const __hip_bfloat16* __restrict__ Xs,
                       const __hip_bfloat16* __restrict__ Xo,
                       const __hip_bfloat16* __restrict__ Wg1,    // 1024 x 1024
                       const __hip_bfloat16* __restrict__ Wg2vo,  // 1024 x 1024
                       const __hip_bfloat16* __restrict__ Wvo,    // 1024 x 1024
                       const float* __restrict__ bg,
                       const float* __restrict__ bvo,
                       float* __restrict__ out) {
  constexpr int BK = 64;
  __shared__ __align__(16) __hip_bfloat16 lA[128 * BK];
  __shared__ __align__(16) __hip_bfloat16 lB[128 * BK];
  __shared__ __align__(16) __hip_bfloat16 lC[128 * BK];

  const int tid  = threadIdx.x;
  const int lane = tid & 63;
  const int wave = tid >> 6;
  const int wm = wave & 1;
  const int wn = wave >> 1;
  int m_idx, n_idx;
  swizzle_mn(m_idx, n_idx);
  const int m0 = m_idx * 128;
  const int n0 = n_idx * 128;

  floatx4 accL[4][4], accC[4][4];
#pragma unroll
  for (int i = 0; i < 4; ++i)
#pragma unroll
    for (int j = 0; j < 4; ++j) {
      floatx4 z = {0.f, 0.f, 0.f, 0.f};
      accL[i][j] = z;
      accC[i][j] = z;
    }

  const int srow = tid >> 3;
  const int scol = (tid & 7) * 8;
  const int fr = lane & 15;
  const int fq = (lane >> 4) * 8;

  // ---- phase 1: accL += Xs @ Wg1^T ----
  for (int k0 = 0; k0 < 1024; k0 += BK) {
    const __hip_bfloat16* srcA = Xs + (size_t)m0 * 1024 + k0;
    const __hip_bfloat16* srcB = Wg1 + (size_t)n0 * 1024 + k0;
#pragma unroll
    for (int p = 0; p < 4; ++p) {
      const int row = p * 32 + srow;
      gl_lds16(srcA + (size_t)row * 1024 + scol, (char*)lA + p * 4096 + tid * 16);
      gl_lds16(srcB + (size_t)row * 1024 + scol, (char*)lB + p * 4096 + tid * 16);
    }
    __syncthreads();

#pragma unroll
    for (int h = 0; h < 2; ++h) {
      short8 af[4], bfr[4];
#pragma unroll
      for (int i = 0; i < 4; ++i)
        af[i] = *(const short8*)((const short*)lA + (wm * 64 + i * 16 + fr) * BK + h * 32 + fq);
#pragma unroll
      for (int j = 0; j < 4; ++j)
        bfr[j] = *(const short8*)((const short*)lB + (wn * 64 + j * 16 + fr) * BK + h * 32 + fq);
#pragma unroll
      for (int i = 0; i < 4; ++i)
#pragma unroll
        for (int j = 0; j < 4; ++j)
          accL[i][j] = __builtin_amdgcn_mfma_f32_16x16x32_bf16(af[i], bfr[j], accL[i][j], 0, 0, 0);
    }
    __syncthreads();
  }

  // ---- phase 2: accL += Xo @ Wg2vo^T ; accC += Xo @ Wvo^T ----
  for (int k0 = 0; k0 < 1024; k0 += BK) {
    const __hip_bfloat16* srcA = Xo + (size_t)m0 * 1024 + k0;
    const __hip_bfloat16* srcB = Wg2vo + (size_t)n0 * 1024 + k0;
    const __hip_bfloat16* srcC = Wvo + (size_t)n0 * 1024 + k0;
#pragma unroll
    for (int p = 0; p < 4; ++p) {
      const int row = p * 32 + srow;
      gl_lds16(srcA + (size_t)row * 1024 + scol, (char*)lA + p * 4096 + tid * 16);
      gl_lds16(srcB + (size_t)row * 1024 + scol, (char*)lB + p * 4096 + tid * 16);
      gl_lds16(srcC + (size_t)row * 1024 + scol, (char*)lC + p * 4096 + tid * 16);
    }
    __syncthreads();

#pragma unroll
    for (int h = 0; h < 2; ++h) {
      short8 af[4], bfr[4], cfr[4];
#pragma unroll
      for (int i = 0; i < 4; ++i)
        af[i] = *(const short8*)((const short*)lA + (wm * 64 + i * 16 + fr) * BK + h * 32 + fq);
#pragma unroll
      for (int j = 0; j < 4; ++j) {
        bfr[j] = *(const short8*)((const short*)lB + (wn * 64 + j * 16 + fr) * BK + h * 32 + fq);
        cfr[j] = *(const short8*)((const short*)lC + (wn * 64 + j * 16 + fr) * BK + h * 32 + fq);
      }
#pragma unroll
      for (int i = 0; i < 4; ++i)
#pragma unroll
        for (int j = 0; j < 4; ++j) {
          accL[i][j] = __builtin_amdgcn_mfma_f32_16x16x32_bf16(af[i], bfr[j], accL[i][j], 0, 0, 0);
          accC[i][j] = __builtin_amdgcn_mfma_f32_16x16x32_bf16(af[i], cfr[j], accC[i][j], 0, 0, 0);
        }
    }
    __syncthreads();
  }

  // epilogue: D mapping col = lane&15, row = (lane>>4)*4 + reg
  const int col = lane & 15;
  const int rq  = (lane >> 4) * 4;
#pragma unroll
  for (int j = 0; j < 4; ++j) {
    const int n = n0 + wn * 64 + j * 16 + col;
    const float bgv = bg[n];
    const float bcv = bvo[n];
#pragma unroll
    for (int i = 0; i < 4; ++i)
#pragma unroll
      for (int r = 0; r < 4; ++r) {
        const int m = m0 + wm * 64 + i * 16 + rq + r;
        const size_t idx = (size_t)m * 1024 + n;
        const float lg = accL[i][j][r] + bgv;
        const float cv = accC[i][j][r] + bcv;
        const float xv = bf2f(Xs[idx]);
        const float g = 1.f / (1.f + __expf(-lg));
        out[idx] = g * xv + (1.f - g) * cv;
      }
  }
}

extern "C" void kernel_launch(void* const* d_in, const int* in_sizes, int n_in,
                              void* d_out, int out_size, void* d_ws, size_t ws_size,
                              hipStream_t stream) {
  (void)in_sizes; (void)n_in; (void)out_size; (void)ws_size;

  const float* text  = (const float*)d_in[0];
  const float* audio = (const float*)d_in[1];
  const float* Wt  = (const float*)d_in[2];
  const float* bt  = (const float*)d_in[3];
  const float* Wa  = (const float*)d_in[4];
  const float* ba  = (const float*)d_in[5];
  // d_in[6..9] = Wq,bq,Wk,bk: dead (softmax over single kv slot == 1)
  const float* Wv  = (const float*)d_in[10];
  const float* bv  = (const float*)d_in[11];
  const float* Wo  = (const float*)d_in[12];
  const float* bo  = (const float*)d_in[13];
  const float* Wgt = (const float*)d_in[14];
  const float* bgt = (const float*)d_in[15];
  const float* Wga = (const float*)d_in[16];
  const float* bga = (const float*)d_in[17];

  const size_t BE = 16384ull * 1024;
  const size_t M1 = 1024ull * 1024;
  float* out = (float*)d_out;

  // ws (persistent across chain): ~79.5 MB (< 92 MB proven-safe budget)
  __hip_bfloat16* p = (__hip_bfloat16*)d_ws;
  __hip_bfloat16* X      = p; p += 2 * BE;         // [t ; a], 64 MB
  __hip_bfloat16* Wt_b   = p; p += 768ull * 1024;
  __hip_bfloat16* Wa_b   = p; p += M1;
  __hip_bfloat16* Wo_b   = p; p += M1;
  __hip_bfloat16* Wvo_b  = p; p += M1;
  __hip_bfloat16* Wg1t_b = p; p += M1;             // Wgt[:, :1024]
  __hip_bfloat16* Wg1a_b = p; p += M1;             // Wga[:, :1024]
  __hip_bfloat16* G2vo   = p; p += 2 * M1;         // [Wgt2.Wvo ; Wga2.Wvo], 2048x1024
  float* bvo  = (float*)p;
  float* bgtp = bvo + 1024;
  float* bgap = bvo + 2048;

  // d_out transient scratch (~66.5 MB, all dead before fused kernels write f32 out)
  __hip_bfloat16* scr     = (__hip_bfloat16*)d_out;
  __hip_bfloat16* text_b  = scr;                          // 16384x768
  __hip_bfloat16* audio_b = scr + 16384ull * 768;         // 16384x1024
  __hip_bfloat16* WvT_b   = audio_b + BE;                 // Wv^T
  __hip_bfloat16* WvoT_b  = WvT_b + M1;                   // Wvo^T
  __hip_bfloat16* G2      = WvoT_b + M1;                  // [Wgt2 ; Wga2], 2048x1024

  dim3 blk(256, 1, 1);

  // ---- converts ----
  cvt_kernel<<<dim3(1, 16384), blk, 0, stream>>>(text, 768, text_b, 768, 192);
  cvt_kernel<<<dim3(1, 16384), blk, 0, stream>>>(audio, 1024, audio_b, 1024, 256);
  cvt_kernel<<<dim3(1, 768), blk, 0, stream>>>(Wt, 1024, Wt_b, 1024, 256);
  cvt_kernel<<<dim3(1, 1024), blk, 0, stream>>>(Wa, 1024, Wa_b, 1024, 256);
  cvt_kernel<<<dim3(1, 1024), blk, 0, stream>>>(Wo, 1024, Wo_b, 1024, 256);
  cvt_t_kernel<<<dim3(32, 32), dim3(32, 8), 0, stream>>>(Wv, WvT_b, 1024, 1024);
  cvt_kernel<<<dim3(1, 1024), blk, 0, stream>>>(Wgt, 2048, Wg1t_b, 1024, 256);        // Wgt1
  cvt_kernel<<<dim3(1, 1024), blk, 0, stream>>>(Wgt + 1024, 2048, G2, 1024, 256);     // Wgt2
  cvt_kernel<<<dim3(1, 1024), blk, 0, stream>>>(Wga, 2048, Wg1a_b, 1024, 256);        // Wga1
  cvt_kernel<<<dim3(1, 1024), blk, 0, stream>>>(Wga + 1024, 2048, G2 + M1, 1024, 256);// Wga2

  // ---- bias folds (f32) ----
  mv_kernel<<<dim3(256), blk, 0, stream>>>(Wo, 1024, 0, bv, bo, bvo);         // bvo = Wo.bv + bo
  mv_kernel<<<dim3(256), blk, 0, stream>>>(Wgt, 2048, 1024, bvo, bgt, bgtp);  // bgt' = Wgt2.bvo + bgt
  mv_kernel<<<dim3(256), blk, 0, stream>>>(Wga, 2048, 1024, bvo, bga, bgap);

  // ---- weight folds (bf16 GEMMs) ----
  // Wvo[n,k]  = sum_m Wo[n,m] WvT[k,m]
  gemm_bt_kernel<<<dim3(8, 8), blk, 0, stream>>>(Wo_b, WvT_b, nullptr, Wvo_b, 1024, 1024, 0);
  // WvoT[k,n] = sum_m WvT[k,m] Wo[n,m]
  gemm_bt_kernel<<<dim3(8, 8), blk, 0, stream>>>(WvT_b, Wo_b, nullptr, WvoT_b, 1024, 1024, 0);
  // G2vo[m,n] = sum_k G2[m,k] WvoT[n,k] = (Wg2.Wvo)[m,n], both modalities stacked
  gemm_bt_kernel<<<dim3(8, 16), blk, 0, stream>>>(G2, WvoT_b, nullptr, G2vo, 1024, 1024, 0);

  // ---- projections ----
  dim3 g1(8, 128);
  gemm_bt_kernel<<<g1, blk, 0, stream>>>(text_b, Wt_b, bt, X, 768, 1024, 0);
  gemm_bt_kernel<<<g1, blk, 0, stream>>>(audio_b, Wa_b, ba, X + BE, 1024, 1024, 0);

  // ---- fused ctx + gate (f32 out, in final position) ----
  fused_gate_kernel<<<g1, blk, 0, stream>>>(X, X + BE, Wg1t_b, G2vo, Wvo_b, bgtp, bvo, out);
  fused_gate_kernel<<<g1, blk, 0, stream>>>(X + BE, X, Wg1a_b, G2vo + M1, Wvo_b, bgap, bvo, out + BE);
}

// Round 3
// 727.640 us; speedup vs baseline: 1.4463x; 1.2735x over previous
//
#include <hip/hip_runtime.h>
#include <hip/hip_bf16.h>

// EmbeddingCrossAttention on MI355X (gfx950). f32 in/out, bf16 MFMA compute.
//
// softmax over single kv slot == 1  =>  ctx = v  =>  everything is affine:
//   t = text@Wt^T+bt ; a = audio@Wa^T+ba
//   t_ctx = a@Wvo^T + bvo            (Wvo = Wo.Wv, bvo = Wo.bv + bo)
//   logit_t = t@Wgt1^T + a@(Wgt2.Wvo)^T + (bgt + Wgt2.bvo)
//   refined_t = g*t + (1-g)*t_ctx, g = sigmoid(logit_t)   (audio swapped)
//
// Round-7 (post-mortem r6: BK=64 helped 258->248 us but MfmaUtil still 16.7%,
// bank conflicts tripled to 3.15e7; stall = per-K-step vmcnt(0) drain):
//   1. Counted-vmcnt double-buffer (T4): BK=32, 2 LDS buffers; issue tile
//      t+1's global_load_lds BEFORE computing tile t; raw s_barrier with
//      inline-asm s_waitcnt vmcnt(N) (N = in-flight loads of t+1, NEVER 0).
//      Loop edges peeled so every vmcnt is a literal. Pointers advance by
//      += BK (no per-iter selects -> avoids round-5's VALU explosion).
//   2. LDS XOR swizzle (T2, both-sides rule #21): slot ^= (row&3), which is
//      per-thread CONSTANT on both sides (staging: (tid>>2)&3 pre-swizzles
//      the global source col; read: fr&3 swizzles the LDS col). 16-way bank
//      conflict -> ~2-way, zero marginal VALU.
//   - kept: m-keyed XCD swizzle, 3 weight-fold GEMMs, fused ctx+gate.

typedef __attribute__((ext_vector_type(8))) short short8;
typedef __attribute__((ext_vector_type(4))) float floatx4;

#define WAITV(N) asm volatile("s_waitcnt vmcnt(" #N ")" ::: "memory")
__device__ __forceinline__ void blockbar() {
  asm volatile("" ::: "memory");
  __builtin_amdgcn_s_barrier();
  asm volatile("" ::: "memory");
}

__device__ __forceinline__ float bf2f(__hip_bfloat16 x) { return __bfloat162float(x); }

__device__ __forceinline__ void gl_lds16(const void* g, void* l) {
  __builtin_amdgcn_global_load_lds(
      (const __attribute__((address_space(1))) unsigned int*)g,
      (__attribute__((address_space(3))) unsigned int*)l,
      16, 0, 0);
}

// XCD-aware block swizzle. All same-m blocks get lid % 8 == m % 8 -> same XCD,
// spaced 8 lids apart -> the A-tile stays in that XCD's L2 across its n-sweep
// (FETCH 147.7 MB vs 290.9 without).
__device__ __forceinline__ void swizzle_mn(int& m_idx, int& n_idx) {
  const int lid = blockIdx.y * 8 + blockIdx.x;
  m_idx = (lid >> 6) * 8 + (lid & 7);
  n_idx = (lid >> 3) & 7;
}

// Strided f32 -> bf16 convert. One row per blockIdx.y, 4 cols per thread.
__global__ __launch_bounds__(256)
void cvt_kernel(const float* __restrict__ src, int sld,
                __hip_bfloat16* __restrict__ dst, int dld, int cols4) {
  const int r = blockIdx.y;
  const int c4 = blockIdx.x * 256 + threadIdx.x;
  if (c4 >= cols4) return;
  const float4 v = *(const float4*)(src + (size_t)r * sld + c4 * 4);
  union { __hip_bfloat16 h[4]; uint2 u; } o;
  o.h[0] = __float2bfloat16(v.x);
  o.h[1] = __float2bfloat16(v.y);
  o.h[2] = __float2bfloat16(v.z);
  o.h[3] = __float2bfloat16(v.w);
  *(uint2*)(dst + (size_t)r * dld + c4 * 4) = o.u;
}

// Transposed convert: dst[c][r] = bf16(src[r][c]), R=C=1024.
__global__ __launch_bounds__(256)
void cvt_t_kernel(const float* __restrict__ src, __hip_bfloat16* __restrict__ dst,
                  int R, int C) {
  __shared__ float tile[32][33];
  const int tx = threadIdx.x, ty = threadIdx.y;  // block (32, 8)
  const int bx = blockIdx.x * 32, by = blockIdx.y * 32;
#pragma unroll
  for (int i = 0; i < 32; i += 8)
    tile[ty + i][tx] = src[(size_t)(by + ty + i) * C + bx + tx];
  __syncthreads();
#pragma unroll
  for (int i = 0; i < 32; i += 8)
    dst[(size_t)(bx + ty + i) * R + by + tx] = __float2bfloat16(tile[tx][ty + i]);
}

// y[r] = sum_k W[r*ld + coff + k] * x[k] + b[r],  K = 1024. 4 rows/block.
__global__ __launch_bounds__(256)
void mv_kernel(const float* __restrict__ W, int ld, int coff,
               const float* __restrict__ x, const float* __restrict__ b,
               float* __restrict__ y) {
  const int lane = threadIdx.x & 63;
  const int row = blockIdx.x * 4 + (threadIdx.x >> 6);
  float acc = 0.f;
  for (int k = lane; k < 1024; k += 64)
    acc += W[(size_t)row * ld + coff + k] * x[k];
#pragma unroll
  for (int off = 32; off > 0; off >>= 1) acc += __shfl_down(acc, off);
  if (lane == 0) y[row] = acc + b[row];
}

// C = A @ W^T (+bias), bf16 out. A row-major (M x K) bf16, W (N x K) bf16.
// C[m*ldc + coff + n]. BK=32, double-buffered LDS, counted vmcnt (never 0 in
// steady state), XOR-swizzled LDS cols. Requires K % 32 == 0, K/32 >= 2.
__global__ __launch_bounds__(256)
void gemm_bt_kernel(const __hip_bfloat16* __restrict__ A,
                    const __hip_bfloat16* __restrict__ W,
                    const float* __restrict__ bias,
                    __hip_bfloat16* __restrict__ C,
                    int K, int ldc, int coff) {
  constexpr int BK = 32;
  __shared__ __align__(16) __hip_bfloat16 lA[2 * 128 * BK];
  __shared__ __align__(16) __hip_bfloat16 lB[2 * 128 * BK];

  const int tid  = threadIdx.x;
  const int lane = tid & 63;
  const int wave = tid >> 6;
  const int wm = wave & 1;
  const int wn = wave >> 1;
  int m_idx, n_idx;
  swizzle_mn(m_idx, n_idx);
  const int m0 = m_idx * 128;
  const int n0 = n_idx * 128;

  floatx4 acc[4][4];
#pragma unroll
  for (int i = 0; i < 4; ++i)
#pragma unroll
    for (int j = 0; j < 4; ++j) {
      floatx4 z = {0.f, 0.f, 0.f, 0.f};
      acc[i][j] = z;
    }

  const int srow  = tid >> 2;                         // 0..63 (rows srow, srow+64)
  const int sc_sw = ((tid & 3) ^ (srow & 3)) * 8;     // pre-swizzled global col (elems)
  const int fr = lane & 15;
  const int fq = (((lane >> 4) ^ (fr & 3))) * 8;      // swizzled LDS read col (elems)

  const __hip_bfloat16* pA = A + (size_t)(m0 + srow) * K + sc_sw;
  const __hip_bfloat16* pW = W + (size_t)(n0 + srow) * K + sc_sw;
  const size_t SR = (size_t)64 * K;

  auto stageAB = [&](int buf) {
    gl_lds16(pA,      (char*)lA + buf * 8192 + tid * 16);
    gl_lds16(pA + SR, (char*)lA + buf * 8192 + 4096 + tid * 16);
    gl_lds16(pW,      (char*)lB + buf * 8192 + tid * 16);
    gl_lds16(pW + SR, (char*)lB + buf * 8192 + 4096 + tid * 16);
    pA += BK; pW += BK;
  };

  auto compute = [&](int cur) {
    const short* sA = (const short*)lA + cur * 4096;
    const short* sB = (const short*)lB + cur * 4096;
    short8 af[4], bfr[4];
#pragma unroll
    for (int i = 0; i < 4; ++i)
      af[i] = *(const short8*)(sA + (wm * 64 + i * 16 + fr) * BK + fq);
#pragma unroll
    for (int j = 0; j < 4; ++j)
      bfr[j] = *(const short8*)(sB + (wn * 64 + j * 16 + fr) * BK + fq);
#pragma unroll
    for (int i = 0; i < 4; ++i)
#pragma unroll
      for (int j = 0; j < 4; ++j)
        acc[i][j] = __builtin_amdgcn_mfma_f32_16x16x32_bf16(af[i], bfr[j], acc[i][j], 0, 0, 0);
  };

  const int NT = K / BK;
  stageAB(0);
  for (int t = 0; t < NT - 1; ++t) {
    const int cur = t & 1;
    stageAB(cur ^ 1);          // prefetch t+1 (4 loads in flight)
    WAITV(4);                  // tile t landed; t+1 stays in flight
    blockbar();
    compute(cur);
    blockbar();                // safe to overwrite buf cur next iter
  }
  WAITV(0);
  blockbar();
  compute((NT - 1) & 1);

  const int col = lane & 15;
  const int rq  = (lane >> 4) * 4;
#pragma unroll
  for (int j = 0; j < 4; ++j) {
    const int n = n0 + wn * 64 + j * 16 + col;
    const float bv = bias ? bias[n] : 0.f;
#pragma unroll
    for (int i = 0; i < 4; ++i)
#pragma unroll
      for (int r = 0; r < 4; ++r) {
        const int m = m0 + wm * 64 + i * 16 + rq + r;
        C[(size_t)m * ldc + coff + n] = __float2bfloat16(acc[i][j][r] + bv);
      }
  }
}

// Fused ctx + gate kernel (per modality), N = 1024:
//   phase 1 (32 tiles): accL += Xs @ Wg1^T
//   phase 2 (32 tiles): accL += Xo @ Wg2vo^T ; accC += Xo @ Wvo^T
//   out[m,n] = g*Xs[m,n] + (1-g)*(accC+bvo),  g = sigmoid(accL+bg)   (f32 out)
__global__ __launch_bounds__(256)
void fused_gate_kernel(const __hip_bfloat16* __restrict__ Xs,
                       const __hip_bfloat16* __restrict__ Xo,
                       const __hip_bfloat16* __restrict__ Wg1,    // 1024 x 1024
                       const __hip_bfloat16* __restrict__ Wg2vo,  // 1024 x 1024
                       const __hip_bfloat16* __restrict__ Wvo,    // 1024 x 1024
                       const float* __restrict__ bg,
                       const float* __restrict__ bvo,
                       float* __restrict__ out) {
  constexpr int BK = 32;
  __shared__ __align__(16) __hip_bfloat16 lA[2 * 128 * BK];
  __shared__ __align__(16) __hip_bfloat16 lB[2 * 128 * BK];
  __shared__ __align__(16) __hip_bfloat16 lC[2 * 128 * BK];

  const int tid  = threadIdx.x;
  const int lane = tid & 63;
  const int wave = tid >> 6;
  const int wm = wave & 1;
  const int wn = wave >> 1;
  int m_idx, n_idx;
  swizzle_mn(m_idx, n_idx);
  const int m0 = m_idx * 128;
  const int n0 = n_idx * 128;

  floatx4 accL[4][4], accC[4][4];
#pragma unroll
  for (int i = 0; i < 4; ++i)
#pragma unroll
    for (int j = 0; j < 4; ++j) {
      floatx4 z = {0.f, 0.f, 0.f, 0.f};
      accL[i][j] = z;
      accC[i][j] = z;
    }

  const int srow  = tid >> 2;
  const int sc_sw = ((tid & 3) ^ (srow & 3)) * 8;
  const int fr = lane & 15;
  const int fq = (((lane >> 4) ^ (fr & 3))) * 8;

  const __hip_bfloat16* pAs = Xs    + (size_t)(m0 + srow) * 1024 + sc_sw;
  const __hip_bfloat16* pB1 = Wg1   + (size_t)(n0 + srow) * 1024 + sc_sw;
  const __hip_bfloat16* pAo = Xo    + (size_t)(m0 + srow) * 1024 + sc_sw;
  const __hip_bfloat16* pB2 = Wg2vo + (size_t)(n0 + srow) * 1024 + sc_sw;
  const __hip_bfloat16* pBv = Wvo   + (size_t)(n0 + srow) * 1024 + sc_sw;
  const size_t SR = (size_t)64 * 1024;

  auto stage1 = [&](int buf) {      // 4 loads
    gl_lds16(pAs,      (char*)lA + buf * 8192 + tid * 16);
    gl_lds16(pAs + SR, (char*)lA + buf * 8192 + 4096 + tid * 16);
    gl_lds16(pB1,      (char*)lB + buf * 8192 + tid * 16);
    gl_lds16(pB1 + SR, (char*)lB + buf * 8192 + 4096 + tid * 16);
    pAs += BK; pB1 += BK;
  };
  auto stage2 = [&](int buf) {      // 6 loads
    gl_lds16(pAo,      (char*)lA + buf * 8192 + tid * 16);
    gl_lds16(pAo + SR, (char*)lA + buf * 8192 + 4096 + tid * 16);
    gl_lds16(pB2,      (char*)lB + buf * 8192 + tid * 16);
    gl_lds16(pB2 + SR, (char*)lB + buf * 8192 + 4096 + tid * 16);
    gl_lds16(pBv,      (char*)lC + buf * 8192 + tid * 16);
    gl_lds16(pBv + SR, (char*)lC + buf * 8192 + 4096 + tid * 16);
    pAo += BK; pB2 += BK; pBv += BK;
  };

  auto comp1 = [&](int cur) {
    const short* sA = (const short*)lA + cur * 4096;
    const short* sB = (const short*)lB + cur * 4096;
    short8 af[4], bfr[4];
#pragma unroll
    for (int i = 0; i < 4; ++i)
      af[i] = *(const short8*)(sA + (wm * 64 + i * 16 + fr) * BK + fq);
#pragma unroll
    for (int j = 0; j < 4; ++j)
      bfr[j] = *(const short8*)(sB + (wn * 64 + j * 16 + fr) * BK + fq);
#pragma unroll
    for (int i = 0; i < 4; ++i)
#pragma unroll
      for (int j = 0; j < 4; ++j)
        accL[i][j] = __builtin_amdgcn_mfma_f32_16x16x32_bf16(af[i], bfr[j], accL[i][j], 0, 0, 0);
  };
  auto comp2 = [&](int cur) {
    const short* sA = (const short*)lA + cur * 4096;
    const short* sB = (const short*)lB + cur * 4096;
    const short* sC = (const short*)lC + cur * 4096;
    short8 af[4], bfr[4], cfr[4];
#pragma unroll
    for (int i = 0; i < 4; ++i)
      af[i] = *(const short8*)(sA + (wm * 64 + i * 16 + fr) * BK + fq);
#pragma unroll
    for (int j = 0; j < 4; ++j) {
      bfr[j] = *(const short8*)(sB + (wn * 64 + j * 16 + fr) * BK + fq);
      cfr[j] = *(const short8*)(sC + (wn * 64 + j * 16 + fr) * BK + fq);
    }
#pragma unroll
    for (int i = 0; i < 4; ++i)
#pragma unroll
      for (int j = 0; j < 4; ++j) {
        accL[i][j] = __builtin_amdgcn_mfma_f32_16x16x32_bf16(af[i], bfr[j], accL[i][j], 0, 0, 0);
        accC[i][j] = __builtin_amdgcn_mfma_f32_16x16x32_bf16(af[i], cfr[j], accC[i][j], 0, 0, 0);
      }
  };

  // phase 1: tiles 0..31 (tile t lives in buf t&1)
  stage1(0);
  for (int t = 0; t < 31; ++t) {
    stage1((t & 1) ^ 1);
    WAITV(4);
    blockbar();
    comp1(t & 1);
    blockbar();
  }
  // last phase-1 tile (buf 1) + prefetch first phase-2 tile (buf 0)
  stage2(0);
  WAITV(6);
  blockbar();
  comp1(1);
  blockbar();
  // phase 2: tiles 0..31 (tile t lives in buf t&1)
  for (int t = 0; t < 31; ++t) {
    stage2((t & 1) ^ 1);
    WAITV(6);
    blockbar();
    comp2(t & 1);
    blockbar();
  }
  WAITV(0);
  blockbar();
  comp2(1);

  // epilogue: D mapping col = lane&15, row = (lane>>4)*4 + reg
  const int col = lane & 15;
  const int rq  = (lane >> 4) * 4;
#pragma unroll
  for (int j = 0; j < 4; ++j) {
    const int n = n0 + wn * 64 + j * 16 + col;
    const float bgv = bg[n];
    const float bcv = bvo[n];
#pragma unroll
    for (int i = 0; i < 4; ++i)
#pragma unroll
      for (int r = 0; r < 4; ++r) {
        const int m = m0 + wm * 64 + i * 16 + rq + r;
        const size_t idx = (size_t)m * 1024 + n;
        const float lg = accL[i][j][r] + bgv;
        const float cv = accC[i][j][r] + bcv;
        const float xv = bf2f(Xs[idx]);
        const float g = 1.f / (1.f + __expf(-lg));
        out[idx] = g * xv + (1.f - g) * cv;
      }
  }
}

extern "C" void kernel_launch(void* const* d_in, const int* in_sizes, int n_in,
                              void* d_out, int out_size, void* d_ws, size_t ws_size,
                              hipStream_t stream) {
  (void)in_sizes; (void)n_in; (void)out_size; (void)ws_size;

  const float* text  = (const float*)d_in[0];
  const float* audio = (const float*)d_in[1];
  const float* Wt  = (const float*)d_in[2];
  const float* bt  = (const float*)d_in[3];
  const float* Wa  = (const float*)d_in[4];
  const float* ba  = (const float*)d_in[5];
  // d_in[6..9] = Wq,bq,Wk,bk: dead (softmax over single kv slot == 1)
  const float* Wv  = (const float*)d_in[10];
  const float* bv  = (const float*)d_in[11];
  const float* Wo  = (const float*)d_in[12];
  const float* bo  = (const float*)d_in[13];
  const float* Wgt = (const float*)d_in[14];
  const float* bgt = (const float*)d_in[15];
  const float* Wga = (const float*)d_in[16];
  const float* bga = (const float*)d_in[17];

  const size_t BE = 16384ull * 1024;
  const size_t M1 = 1024ull * 1024;
  float* out = (float*)d_out;

  // ws (persistent across chain): ~79.5 MB (< 92 MB proven-safe budget)
  __hip_bfloat16* p = (__hip_bfloat16*)d_ws;
  __hip_bfloat16* X      = p; p += 2 * BE;         // [t ; a], 64 MB
  __hip_bfloat16* Wt_b   = p; p += 768ull * 1024;
  __hip_bfloat16* Wa_b   = p; p += M1;
  __hip_bfloat16* Wo_b   = p; p += M1;
  __hip_bfloat16* Wvo_b  = p; p += M1;
  __hip_bfloat16* Wg1t_b = p; p += M1;             // Wgt[:, :1024]
  __hip_bfloat16* Wg1a_b = p; p += M1;             // Wga[:, :1024]
  __hip_bfloat16* G2vo   = p; p += 2 * M1;         // [Wgt2.Wvo ; Wga2.Wvo], 2048x1024
  float* bvo  = (float*)p;
  float* bgtp = bvo + 1024;
  float* bgap = bvo + 2048;

  // d_out transient scratch (~66.5 MB, all dead before fused kernels write f32 out)
  __hip_bfloat16* scr     = (__hip_bfloat16*)d_out;
  __hip_bfloat16* text_b  = scr;                          // 16384x768
  __hip_bfloat16* audio_b = scr + 16384ull * 768;         // 16384x1024
  __hip_bfloat16* WvT_b   = audio_b + BE;                 // Wv^T
  __hip_bfloat16* WvoT_b  = WvT_b + M1;                   // Wvo^T
  __hip_bfloat16* G2      = WvoT_b + M1;                  // [Wgt2 ; Wga2], 2048x1024

  dim3 blk(256, 1, 1);

  // ---- converts ----
  cvt_kernel<<<dim3(1, 16384), blk, 0, stream>>>(text, 768, text_b, 768, 192);
  cvt_kernel<<<dim3(1, 16384), blk, 0, stream>>>(audio, 1024, audio_b, 1024, 256);
  cvt_kernel<<<dim3(1, 768), blk, 0, stream>>>(Wt, 1024, Wt_b, 1024, 256);
  cvt_kernel<<<dim3(1, 1024), blk, 0, stream>>>(Wa, 1024, Wa_b, 1024, 256);
  cvt_kernel<<<dim3(1, 1024), blk, 0, stream>>>(Wo, 1024, Wo_b, 1024, 256);
  cvt_t_kernel<<<dim3(32, 32), dim3(32, 8), 0, stream>>>(Wv, WvT_b, 1024, 1024);
  cvt_kernel<<<dim3(1, 1024), blk, 0, stream>>>(Wgt, 2048, Wg1t_b, 1024, 256);        // Wgt1
  cvt_kernel<<<dim3(1, 1024), blk, 0, stream>>>(Wgt + 1024, 2048, G2, 1024, 256);     // Wgt2
  cvt_kernel<<<dim3(1, 1024), blk, 0, stream>>>(Wga, 2048, Wg1a_b, 1024, 256);        // Wga1
  cvt_kernel<<<dim3(1, 1024), blk, 0, stream>>>(Wga + 1024, 2048, G2 + M1, 1024, 256);// Wga2

  // ---- bias folds (f32) ----
  mv_kernel<<<dim3(256), blk, 0, stream>>>(Wo, 1024, 0, bv, bo, bvo);         // bvo = Wo.bv + bo
  mv_kernel<<<dim3(256), blk, 0, stream>>>(Wgt, 2048, 1024, bvo, bgt, bgtp);  // bgt' = Wgt2.bvo + bgt
  mv_kernel<<<dim3(256), blk, 0, stream>>>(Wga, 2048, 1024, bvo, bga, bgap);

  // ---- weight folds (bf16 GEMMs) ----
  // Wvo[n,k]  = sum_m Wo[n,m] WvT[k,m]
  gemm_bt_kernel<<<dim3(8, 8), blk, 0, stream>>>(Wo_b, WvT_b, nullptr, Wvo_b, 1024, 1024, 0);
  // WvoT[k,n] = sum_m WvT[k,m] Wo[n,m]
  gemm_bt_kernel<<<dim3(8, 8), blk, 0, stream>>>(WvT_b, Wo_b, nullptr, WvoT_b, 1024, 1024, 0);
  // G2vo[m,n] = sum_k G2[m,k] WvoT[n,k] = (Wg2.Wvo)[m,n], both modalities stacked
  gemm_bt_kernel<<<dim3(8, 16), blk, 0, stream>>>(G2, WvoT_b, nullptr, G2vo, 1024, 1024, 0);

  // ---- projections ----
  dim3 g1(8, 128);
  gemm_bt_kernel<<<g1, blk, 0, stream>>>(text_b, Wt_b, bt, X, 768, 1024, 0);
  gemm_bt_kernel<<<g1, blk, 0, stream>>>(audio_b, Wa_b, ba, X + BE, 1024, 1024, 0);

  // ---- fused ctx + gate (f32 out, in final position) ----
  fused_gate_kernel<<<g1, blk, 0, stream>>>(X, X + BE, Wg1t_b, G2vo, Wvo_b, bgtp, bvo, out);
  fused_gate_kernel<<<g1, blk, 0, stream>>>(X + BE, X, Wg1a_b, G2vo + M1, Wvo_b, bgap, bvo, out + BE);
}

// Round 4
// 639.863 us; speedup vs baseline: 1.6447x; 1.1372x over previous
//
#include <hip/hip_runtime.h>
#include <hip/hip_bf16.h>

// EmbeddingCrossAttention on MI355X (gfx950). f32 in/out, bf16 MFMA compute.
//
// softmax over single kv slot == 1  =>  ctx = v  =>  everything is affine:
//   t = text@Wt^T+bt ; a = audio@Wa^T+ba
//   t_ctx = a@Wvo^T + bvo            (Wvo = Wo.Wv, bvo = Wo.bv + bo)
//   logit_t = t@Wgt1^T + a@(Wgt2.Wvo)^T + (bgt + Wgt2.bvo)
//   refined_t = g*t + (1-g)*t_ctx, g = sigmoid(logit_t)   (audio swapped)
//
// Round-8 (post-mortem r7: fused 148us, total 728; non-GEMM chain ~270us is
// launch/ramp-bound — identical 431/432us across r2/r3 despite 40% GEMM gain):
//   1. Dispatch consolidation 18 -> 9: 9-job cvt kernel; projections merged
//      (1 dispatch, per-job K); fused merged (1 dispatch, modality by m_idx);
//      mv pair batched; fold2 GEMM replaced by bf16 transpose.
//   2. gemm template: 3-buffer/ONE-barrier pipeline (race-free: stage target
//      (t+1)%3 vs worst concurrent reader (t-1)%3, distance 2 mod 3; per-wave
//      WAITV + collective barrier => all waves' tile-t loads landed).
//      LDS 48KB -> still 3 blocks/CU.
//   3. fused inner loop kept EXACTLY round-3 (proven 148us; 3-stream 3-buf
//      would cost a resident block — isolated to a later experiment).

typedef __attribute__((ext_vector_type(8))) short short8;
typedef __attribute__((ext_vector_type(4))) float floatx4;

#define WAITV(N) asm volatile("s_waitcnt vmcnt(" #N ")" ::: "memory")
__device__ __forceinline__ void blockbar() {
  asm volatile("" ::: "memory");
  __builtin_amdgcn_s_barrier();
  asm volatile("" ::: "memory");
}

__device__ __forceinline__ float bf2f(__hip_bfloat16 x) { return __bfloat162float(x); }

__device__ __forceinline__ void gl_lds16(const void* g, void* l) {
  __builtin_amdgcn_global_load_lds(
      (const __attribute__((address_space(1))) unsigned int*)g,
      (__attribute__((address_space(3))) unsigned int*)l,
      16, 0, 0);
}

// XCD-aware block swizzle: same-m blocks share lid%8 -> same XCD, 8 lids apart
// -> A-tile stays L2-resident across its n-sweep.
__device__ __forceinline__ void swizzle_mn(int& m_idx, int& n_idx) {
  const int lid = blockIdx.y * 8 + blockIdx.x;
  m_idx = (lid >> 6) * 8 + (lid & 7);
  n_idx = (lid >> 3) & 7;
}

// ---- 9-job strided f32 -> bf16 convert; 1 block per row ----
struct CvtJob { const float* src; __hip_bfloat16* dst; int sld, dld, cols4, rowbase; };
struct CvtJobs { CvtJob j[9]; };

__global__ __launch_bounds__(256)
void cvt9_kernel(CvtJobs a) {
  const int r = blockIdx.x;
  int ji = 0;
#pragma unroll
  for (int i = 1; i < 9; ++i) ji += (r >= a.j[i].rowbase) ? 1 : 0;
  const CvtJob J = a.j[ji];
  const int rr = r - J.rowbase;
  const int c4 = threadIdx.x;
  if (c4 >= J.cols4) return;
  const float4 v = *(const float4*)(J.src + (size_t)rr * J.sld + c4 * 4);
  union { __hip_bfloat16 h[4]; uint2 u; } o;
  o.h[0] = __float2bfloat16(v.x);
  o.h[1] = __float2bfloat16(v.y);
  o.h[2] = __float2bfloat16(v.z);
  o.h[3] = __float2bfloat16(v.w);
  *(uint2*)(J.dst + (size_t)rr * J.dld + c4 * 4) = o.u;
}

// Transposed convert: dst[c][r] = bf16(src[r][c]), R=C=1024 (f32 in).
__global__ __launch_bounds__(256)
void cvt_t_kernel(const float* __restrict__ src, __hip_bfloat16* __restrict__ dst,
                  int R, int C) {
  __shared__ float tile[32][33];
  const int tx = threadIdx.x, ty = threadIdx.y;  // block (32, 8)
  const int bx = blockIdx.x * 32, by = blockIdx.y * 32;
#pragma unroll
  for (int i = 0; i < 32; i += 8)
    tile[ty + i][tx] = src[(size_t)(by + ty + i) * C + bx + tx];
  __syncthreads();
#pragma unroll
  for (int i = 0; i < 32; i += 8)
    dst[(size_t)(bx + ty + i) * R + by + tx] = __float2bfloat16(tile[tx][ty + i]);
}

// bf16 1024x1024 transpose: dst[c][r] = src[r][c].
__global__ __launch_bounds__(256)
void tr_bf16_kernel(const __hip_bfloat16* __restrict__ src,
                    __hip_bfloat16* __restrict__ dst) {
  __shared__ __hip_bfloat16 tile[32][33];
  const int tx = threadIdx.x, ty = threadIdx.y;  // block (32, 8)
  const int bx = blockIdx.x * 32, by = blockIdx.y * 32;
#pragma unroll
  for (int i = 0; i < 32; i += 8)
    tile[ty + i][tx] = src[(size_t)(by + ty + i) * 1024 + bx + tx];
  __syncthreads();
#pragma unroll
  for (int i = 0; i < 32; i += 8)
    dst[(size_t)(bx + ty + i) * 1024 + by + tx] = tile[tx][ty + i];
}

// y[r] = sum_k W[r*ld + coff + k] * x[k] + b[r],  K = 1024. 4 rows/block.
__global__ __launch_bounds__(256)
void mv_kernel(const float* __restrict__ W, int ld, int coff,
               const float* __restrict__ x, const float* __restrict__ b,
               float* __restrict__ y) {
  const int lane = threadIdx.x & 63;
  const int row = blockIdx.x * 4 + (threadIdx.x >> 6);
  float acc = 0.f;
  for (int k = lane; k < 1024; k += 64)
    acc += W[(size_t)row * ld + coff + k] * x[k];
#pragma unroll
  for (int off = 32; off > 0; off >>= 1) acc += __shfl_down(acc, off);
  if (lane == 0) y[row] = acc + b[row];
}

// Two mv jobs in one launch (both ld=2048, coff=1024, x=bvo). blockIdx.y picks.
__global__ __launch_bounds__(256)
void mv2_kernel(const float* __restrict__ W0, const float* __restrict__ W1,
                const float* __restrict__ x,
                const float* __restrict__ b0, const float* __restrict__ b1,
                float* __restrict__ y0, float* __restrict__ y1) {
  const float* W = blockIdx.y ? W1 : W0;
  const float* b = blockIdx.y ? b1 : b0;
  float* y = blockIdx.y ? y1 : y0;
  const int lane = threadIdx.x & 63;
  const int row = blockIdx.x * 4 + (threadIdx.x >> 6);
  float acc = 0.f;
  for (int k = lane; k < 1024; k += 64)
    acc += W[(size_t)row * 2048 + 1024 + k] * x[k];
#pragma unroll
  for (int off = 32; off > 0; off >>= 1) acc += __shfl_down(acc, off);
  if (lane == 0) y[row] = acc + b[row];
}

// C = A @ W^T (+bias), bf16 out. Two jobs split on m_idx (mSplit). BK=32,
// 3-buffer LDS, ONE barrier per K-tile, counted vmcnt (never 0 in steady state).
struct GemmJob {
  const __hip_bfloat16* A; const __hip_bfloat16* W;
  const float* bias; __hip_bfloat16* C; int K; int ldc; int coff;
};

__global__ __launch_bounds__(256)
void gemm_bt2_kernel(GemmJob j0, GemmJob j1, int mSplit) {
  constexpr int BK = 32;
  __shared__ __align__(16) __hip_bfloat16 lA[3 * 128 * BK];
  __shared__ __align__(16) __hip_bfloat16 lB[3 * 128 * BK];

  const int tid  = threadIdx.x;
  const int lane = tid & 63;
  const int wave = tid >> 6;
  const int wm = wave & 1;
  const int wn = wave >> 1;
  int m_idx, n_idx;
  swizzle_mn(m_idx, n_idx);
  const bool sec = m_idx >= mSplit;
  const GemmJob J = sec ? j1 : j0;
  const int m0 = (sec ? m_idx - mSplit : m_idx) * 128;
  const int n0 = n_idx * 128;
  const int K = J.K;

  floatx4 acc[4][4];
#pragma unroll
  for (int i = 0; i < 4; ++i)
#pragma unroll
    for (int j = 0; j < 4; ++j) {
      floatx4 z = {0.f, 0.f, 0.f, 0.f};
      acc[i][j] = z;
    }

  const int srow  = tid >> 2;
  const int sc_sw = ((tid & 3) ^ (srow & 3)) * 8;
  const int fr = lane & 15;
  const int fq = (((lane >> 4) ^ (fr & 3))) * 8;

  const __hip_bfloat16* pA = J.A + (size_t)(m0 + srow) * K + sc_sw;
  const __hip_bfloat16* pW = J.W + (size_t)(n0 + srow) * K + sc_sw;
  const size_t SR = (size_t)64 * K;

  int sOff = 0;
  auto stageAB = [&]() {
    gl_lds16(pA,      (char*)lA + sOff + tid * 16);
    gl_lds16(pA + SR, (char*)lA + sOff + 4096 + tid * 16);
    gl_lds16(pW,      (char*)lB + sOff + tid * 16);
    gl_lds16(pW + SR, (char*)lB + sOff + 4096 + tid * 16);
    pA += BK; pW += BK;
    sOff = (sOff == 16384) ? 0 : sOff + 8192;
  };

  auto compute = [&](int cOff) {
    const short* sA = (const short*)((const char*)lA + cOff);
    const short* sB = (const short*)((const char*)lB + cOff);
    short8 af[4], bfr[4];
#pragma unroll
    for (int i = 0; i < 4; ++i)
      af[i] = *(const short8*)(sA + (wm * 64 + i * 16 + fr) * BK + fq);
#pragma unroll
    for (int j = 0; j < 4; ++j)
      bfr[j] = *(const short8*)(sB + (wn * 64 + j * 16 + fr) * BK + fq);
#pragma unroll
    for (int i = 0; i < 4; ++i)
#pragma unroll
      for (int j = 0; j < 4; ++j)
        acc[i][j] = __builtin_amdgcn_mfma_f32_16x16x32_bf16(af[i], bfr[j], acc[i][j], 0, 0, 0);
  };

  const int NT = K / BK;
  int cOff = 0;
  stageAB();                      // tile 0 -> buf 0
  for (int t = 0; t < NT - 1; ++t) {
    stageAB();                    // tile t+1 -> buf (t+1)%3
    WAITV(4);                     // tile t landed; t+1 in flight
    blockbar();                   // single barrier per tile
    compute(cOff);
    cOff = (cOff == 16384) ? 0 : cOff + 8192;
  }
  WAITV(0);
  blockbar();
  compute(cOff);

  const int col = lane & 15;
  const int rq  = (lane >> 4) * 4;
#pragma unroll
  for (int j = 0; j < 4; ++j) {
    const int n = n0 + wn * 64 + j * 16 + col;
    const float bv = J.bias ? J.bias[n] : 0.f;
#pragma unroll
    for (int i = 0; i < 4; ++i)
#pragma unroll
      for (int r = 0; r < 4; ++r) {
        const int m = m0 + wm * 64 + i * 16 + rq + r;
        J.C[(size_t)m * J.ldc + J.coff + n] = __float2bfloat16(acc[i][j][r] + bv);
      }
  }
}

// Fused ctx + gate, BOTH modalities in one dispatch (m_idx >= 128 -> audio):
//   phase 1 (32 tiles): accL += Xs @ Wg1^T
//   phase 2 (32 tiles): accL += Xo @ Wg2vo^T ; accC += Xo @ Wvo^T
//   out[m,n] = g*Xs[m,n] + (1-g)*(accC+bvo),  g = sigmoid(accL+bg)
// Inner loop EXACTLY round-3 (2-buf, counted vmcnt) — proven 148 us.
__global__ __launch_bounds__(256)
void fused_gate_kernel(const __hip_bfloat16* __restrict__ Xt,
                       const __hip_bfloat16* __restrict__ Xa,
                       const __hip_bfloat16* __restrict__ Wg1t,
                       const __hip_bfloat16* __restrict__ Wg1a,
                       const __hip_bfloat16* __restrict__ G2vo,   // 2048 x 1024
                       const __hip_bfloat16* __restrict__ Wvo,    // 1024 x 1024
                       const float* __restrict__ bgt,
                       const float* __restrict__ bga,
                       const float* __restrict__ bvo,
                       float* __restrict__ out) {
  constexpr int BK = 32;
  __shared__ __align__(16) __hip_bfloat16 lA[2 * 128 * BK];
  __shared__ __align__(16) __hip_bfloat16 lB[2 * 128 * BK];
  __shared__ __align__(16) __hip_bfloat16 lC[2 * 128 * BK];

  const int tid  = threadIdx.x;
  const int lane = tid & 63;
  const int wave = tid >> 6;
  const int wm = wave & 1;
  const int wn = wave >> 1;
  int m_idx, n_idx;
  swizzle_mn(m_idx, n_idx);
  const bool aud = m_idx >= 128;
  const int m0 = (m_idx & 127) * 128;
  const int n0 = n_idx * 128;

  const size_t M1 = 1024ull * 1024;
  const __hip_bfloat16* Xs  = aud ? Xa : Xt;
  const __hip_bfloat16* Xo  = aud ? Xt : Xa;
  const __hip_bfloat16* Wg1 = aud ? Wg1a : Wg1t;
  const __hip_bfloat16* Wg2vo = G2vo + (aud ? M1 : 0);
  const float* bg = aud ? bga : bgt;
  float* po = out + (aud ? (size_t)16384 * 1024 : 0);

  floatx4 accL[4][4], accC[4][4];
#pragma unroll
  for (int i = 0; i < 4; ++i)
#pragma unroll
    for (int j = 0; j < 4; ++j) {
      floatx4 z = {0.f, 0.f, 0.f, 0.f};
      accL[i][j] = z;
      accC[i][j] = z;
    }

  const int srow  = tid >> 2;
  const int sc_sw = ((tid & 3) ^ (srow & 3)) * 8;
  const int fr = lane & 15;
  const int fq = (((lane >> 4) ^ (fr & 3))) * 8;

  const __hip_bfloat16* pAs = Xs    + (size_t)(m0 + srow) * 1024 + sc_sw;
  const __hip_bfloat16* pB1 = Wg1   + (size_t)(n0 + srow) * 1024 + sc_sw;
  const __hip_bfloat16* pAo = Xo    + (size_t)(m0 + srow) * 1024 + sc_sw;
  const __hip_bfloat16* pB2 = Wg2vo + (size_t)(n0 + srow) * 1024 + sc_sw;
  const __hip_bfloat16* pBv = Wvo   + (size_t)(n0 + srow) * 1024 + sc_sw;
  const size_t SR = (size_t)64 * 1024;

  auto stage1 = [&](int buf) {      // 4 loads
    gl_lds16(pAs,      (char*)lA + buf * 8192 + tid * 16);
    gl_lds16(pAs + SR, (char*)lA + buf * 8192 + 4096 + tid * 16);
    gl_lds16(pB1,      (char*)lB + buf * 8192 + tid * 16);
    gl_lds16(pB1 + SR, (char*)lB + buf * 8192 + 4096 + tid * 16);
    pAs += BK; pB1 += BK;
  };
  auto stage2 = [&](int buf) {      // 6 loads
    gl_lds16(pAo,      (char*)lA + buf * 8192 + tid * 16);
    gl_lds16(pAo + SR, (char*)lA + buf * 8192 + 4096 + tid * 16);
    gl_lds16(pB2,      (char*)lB + buf * 8192 + tid * 16);
    gl_lds16(pB2 + SR, (char*)lB + buf * 8192 + 4096 + tid * 16);
    gl_lds16(pBv,      (char*)lC + buf * 8192 + tid * 16);
    gl_lds16(pBv + SR, (char*)lC + buf * 8192 + 4096 + tid * 16);
    pAo += BK; pB2 += BK; pBv += BK;
  };

  auto comp1 = [&](int cur) {
    const short* sA = (const short*)lA + cur * 4096;
    const short* sB = (const short*)lB + cur * 4096;
    short8 af[4], bfr[4];
#pragma unroll
    for (int i = 0; i < 4; ++i)
      af[i] = *(const short8*)(sA + (wm * 64 + i * 16 + fr) * BK + fq);
#pragma unroll
    for (int j = 0; j < 4; ++j)
      bfr[j] = *(const short8*)(sB + (wn * 64 + j * 16 + fr) * BK + fq);
#pragma unroll
    for (int i = 0; i < 4; ++i)
#pragma unroll
      for (int j = 0; j < 4; ++j)
        accL[i][j] = __builtin_amdgcn_mfma_f32_16x16x32_bf16(af[i], bfr[j], accL[i][j], 0, 0, 0);
  };
  auto comp2 = [&](int cur) {
    const short* sA = (const short*)lA + cur * 4096;
    const short* sB = (const short*)lB + cur * 4096;
    const short* sC = (const short*)lC + cur * 4096;
    short8 af[4], bfr[4], cfr[4];
#pragma unroll
    for (int i = 0; i < 4; ++i)
      af[i] = *(const short8*)(sA + (wm * 64 + i * 16 + fr) * BK + fq);
#pragma unroll
    for (int j = 0; j < 4; ++j) {
      bfr[j] = *(const short8*)(sB + (wn * 64 + j * 16 + fr) * BK + fq);
      cfr[j] = *(const short8*)(sC + (wn * 64 + j * 16 + fr) * BK + fq);
    }
#pragma unroll
    for (int i = 0; i < 4; ++i)
#pragma unroll
      for (int j = 0; j < 4; ++j) {
        accL[i][j] = __builtin_amdgcn_mfma_f32_16x16x32_bf16(af[i], bfr[j], accL[i][j], 0, 0, 0);
        accC[i][j] = __builtin_amdgcn_mfma_f32_16x16x32_bf16(af[i], cfr[j], accC[i][j], 0, 0, 0);
      }
  };

  // phase 1: tiles 0..31 (tile t in buf t&1)
  stage1(0);
  for (int t = 0; t < 31; ++t) {
    stage1((t & 1) ^ 1);
    WAITV(4);
    blockbar();
    comp1(t & 1);
    blockbar();
  }
  // last phase-1 tile (buf 1) + prefetch first phase-2 tile (buf 0)
  stage2(0);
  WAITV(6);
  blockbar();
  comp1(1);
  blockbar();
  // phase 2: tiles 0..31
  for (int t = 0; t < 31; ++t) {
    stage2((t & 1) ^ 1);
    WAITV(6);
    blockbar();
    comp2(t & 1);
    blockbar();
  }
  WAITV(0);
  blockbar();
  comp2(1);

  // epilogue: D mapping col = lane&15, row = (lane>>4)*4 + reg
  const int col = lane & 15;
  const int rq  = (lane >> 4) * 4;
#pragma unroll
  for (int j = 0; j < 4; ++j) {
    const int n = n0 + wn * 64 + j * 16 + col;
    const float bgv = bg[n];
    const float bcv = bvo[n];
#pragma unroll
    for (int i = 0; i < 4; ++i)
#pragma unroll
      for (int r = 0; r < 4; ++r) {
        const int m = m0 + wm * 64 + i * 16 + rq + r;
        const size_t idx = (size_t)m * 1024 + n;
        const float lg = accL[i][j][r] + bgv;
        const float cv = accC[i][j][r] + bcv;
        const float xv = bf2f(Xs[idx]);
        const float g = 1.f / (1.f + __expf(-lg));
        po[idx] = g * xv + (1.f - g) * cv;
      }
  }
}

extern "C" void kernel_launch(void* const* d_in, const int* in_sizes, int n_in,
                              void* d_out, int out_size, void* d_ws, size_t ws_size,
                              hipStream_t stream) {
  (void)in_sizes; (void)n_in; (void)out_size; (void)ws_size;

  const float* text  = (const float*)d_in[0];
  const float* audio = (const float*)d_in[1];
  const float* Wt  = (const float*)d_in[2];
  const float* bt  = (const float*)d_in[3];
  const float* Wa  = (const float*)d_in[4];
  const float* ba  = (const float*)d_in[5];
  // d_in[6..9] = Wq,bq,Wk,bk: dead (softmax over single kv slot == 1)
  const float* Wv  = (const float*)d_in[10];
  const float* bv  = (const float*)d_in[11];
  const float* Wo  = (const float*)d_in[12];
  const float* bo  = (const float*)d_in[13];
  const float* Wgt = (const float*)d_in[14];
  const float* bgt = (const float*)d_in[15];
  const float* Wga = (const float*)d_in[16];
  const float* bga = (const float*)d_in[17];

  const size_t BE = 16384ull * 1024;
  const size_t M1 = 1024ull * 1024;
  float* out = (float*)d_out;

  // ws (persistent): ~79.5 MB (< 92 MB proven-safe budget)
  __hip_bfloat16* p = (__hip_bfloat16*)d_ws;
  __hip_bfloat16* X      = p; p += 2 * BE;         // [t ; a], 64 MB
  __hip_bfloat16* Wt_b   = p; p += 768ull * 1024;
  __hip_bfloat16* Wa_b   = p; p += M1;
  __hip_bfloat16* Wo_b   = p; p += M1;
  __hip_bfloat16* Wvo_b  = p; p += M1;
  __hip_bfloat16* Wg1t_b = p; p += M1;             // Wgt[:, :1024]
  __hip_bfloat16* Wg1a_b = p; p += M1;             // Wga[:, :1024]
  __hip_bfloat16* G2vo   = p; p += 2 * M1;         // [Wgt2.Wvo ; Wga2.Wvo]
  float* bvo  = (float*)p;
  float* bgtp = bvo + 1024;
  float* bgap = bvo + 2048;

  // d_out transient scratch (~64.5 MB, all dead before fused writes f32 out)
  __hip_bfloat16* scr     = (__hip_bfloat16*)d_out;
  __hip_bfloat16* text_b  = scr;                          // 16384x768
  __hip_bfloat16* audio_b = scr + 16384ull * 768;         // 16384x1024
  __hip_bfloat16* WvT_b   = audio_b + BE;                 // Wv^T (bf16)
  __hip_bfloat16* WvoT_b  = WvT_b + M1;                   // Wvo^T (bf16)
  __hip_bfloat16* G2      = WvoT_b + M1;                  // [Wgt2 ; Wga2]

  dim3 blk(256, 1, 1);

  // ---- all f32->bf16 converts in ONE dispatch (9 jobs, 1 block/row) ----
  CvtJobs cj;
  cj.j[0] = { text,       text_b,  768,  768,  192, 0 };
  cj.j[1] = { audio,      audio_b, 1024, 1024, 256, 16384 };
  cj.j[2] = { Wt,         Wt_b,    1024, 1024, 256, 32768 };  // flat 768x1024 view
  cj.j[3] = { Wa,         Wa_b,    1024, 1024, 256, 33536 };
  cj.j[4] = { Wo,         Wo_b,    1024, 1024, 256, 34560 };
  cj.j[5] = { Wgt,        Wg1t_b,  2048, 1024, 256, 35584 };  // Wgt1
  cj.j[6] = { Wgt + 1024, G2,      2048, 1024, 256, 36608 };  // Wgt2
  cj.j[7] = { Wga,        Wg1a_b,  2048, 1024, 256, 37632 };  // Wga1
  cj.j[8] = { Wga + 1024, G2 + M1, 2048, 1024, 256, 38656 };  // Wga2
  cvt9_kernel<<<dim3(39680), blk, 0, stream>>>(cj);
  cvt_t_kernel<<<dim3(32, 32), dim3(32, 8), 0, stream>>>(Wv, WvT_b, 1024, 1024);

  // ---- bias folds (f32) ----
  mv_kernel<<<dim3(256), blk, 0, stream>>>(Wo, 1024, 0, bv, bo, bvo);  // bvo = Wo.bv + bo
  mv2_kernel<<<dim3(256, 2), blk, 0, stream>>>(Wgt, Wga, bvo, bgt, bga, bgtp, bgap);

  // ---- weight folds ----
  GemmJob f1 = { Wo_b, WvT_b, nullptr, Wvo_b, 1024, 1024, 0 };   // Wvo = Wo.Wv
  gemm_bt2_kernel<<<dim3(8, 8), blk, 0, stream>>>(f1, f1, 999);
  tr_bf16_kernel<<<dim3(32, 32), dim3(32, 8), 0, stream>>>(Wvo_b, WvoT_b);
  GemmJob f3 = { G2, WvoT_b, nullptr, G2vo, 1024, 1024, 0 };     // [Wg2.Wvo] stacked
  gemm_bt2_kernel<<<dim3(8, 16), blk, 0, stream>>>(f3, f3, 999);

  // ---- projections (both modalities, one dispatch) ----
  GemmJob pt = { text_b,  Wt_b, bt, X,      768,  1024, 0 };
  GemmJob pa = { audio_b, Wa_b, ba, X + BE, 1024, 1024, 0 };
  gemm_bt2_kernel<<<dim3(8, 256), blk, 0, stream>>>(pt, pa, 128);

  // ---- fused ctx + gate (both modalities, one dispatch, f32 out) ----
  fused_gate_kernel<<<dim3(8, 256), blk, 0, stream>>>(
      X, X + BE, Wg1t_b, Wg1a_b, G2vo, Wvo_b, bgtp, bgap, bvo, out);
}